// Round 1
// baseline (142.375 us; speedup 1.0000x reference)
//
#include <hip/hip_runtime.h>

// N=512, S=64, C=1024, B=10, PAD=0, NEG=-1e9
#define NN 512
#define SS 64
#define CC 1024
#define BB 10
#define SH 32              // fallback fused kernel: s-values per block
#define SH2 8              // writer kernel: s-values per block

typedef float nfloat4 __attribute__((ext_vector_type(4)));

// ======================= Phase 1: per-n stats =======================
// One block (one wave, 64 threads) per n. Computes the histogram once,
// the global max+sumexp once, and all 64 per-s LSEs. Writes cnt row and
// lse row to workspace; also writes out_v (zeros).
__global__ __launch_bounds__(64) void spop_stats_kernel(
    const int* __restrict__ ban_ids,    // [N,S,B]
    const int* __restrict__ item_ids,   // [N,S]
    float* __restrict__ ws_cnt,         // [N,C]
    float* __restrict__ ws_lse,         // [N,S]
    float* __restrict__ out_v)          // [N,S]
{
    const int n   = blockIdx.x;
    const int tid = threadIdx.x;        // 0..63, exactly one wave

    __shared__ __align__(16) float cnt[CC];

#pragma unroll
    for (int k = 0; k < 4; ++k)
        *reinterpret_cast<float4*>(&cnt[(tid + 64 * k) * 4]) =
            make_float4(0.f, 0.f, 0.f, 0.f);
    __syncthreads();

    // histogram of non-pad items, dropping the LAST non-pad element
    const int id = item_ids[n * SS + tid];
    const bool nonpad = (id != 0);
    const unsigned long long m = __ballot(nonpad);
    const int last = 63 - __clzll(m | 1ull);
    if (nonpad && tid != last) atomicAdd(&cnt[id], 1.0f);
    __syncthreads();

    // each thread owns 16 classes (4x float4); block max then sumexp
    float4 v[4];
#pragma unroll
    for (int k = 0; k < 4; ++k)
        v[k] = *reinterpret_cast<const float4*>(&cnt[(tid + 64 * k) * 4]);

    float mx = v[0].x;
#pragma unroll
    for (int k = 0; k < 4; ++k)
        mx = fmaxf(mx, fmaxf(fmaxf(v[k].x, v[k].y), fmaxf(v[k].z, v[k].w)));
#pragma unroll
    for (int off = 32; off >= 1; off >>= 1)      // butterfly: all lanes get max
        mx = fmaxf(mx, __shfl_xor(mx, off));

    float se = 0.f;
#pragma unroll
    for (int k = 0; k < 4; ++k)
        se += __expf(v[k].x - mx) + __expf(v[k].y - mx) +
              __expf(v[k].z - mx) + __expf(v[k].w - mx);
#pragma unroll
    for (int off = 32; off >= 1; off >>= 1)      // butterfly: all lanes get sum
        se += __shfl_xor(se, off);

    // per-s lse: thread tid handles s = tid (S == 64)
    int ban[BB];
#pragma unroll
    for (int j = 0; j < BB; ++j)
        ban[j] = ban_ids[(n * SS + tid) * BB + j];
    float bsum = 0.f;
#pragma unroll
    for (int j = 0; j < BB; ++j) {
        bool dup = false;
#pragma unroll
        for (int k = 0; k < BB; ++k)
            if (k < j) dup |= (ban[k] == ban[j]);
        if (!dup) bsum += __expf(cnt[ban[j]] - mx);
    }
    const float valid = fmaxf(se - bsum, 1e-30f);
    ws_lse[n * SS + tid] = mx + __logf(valid);
    out_v[n * SS + tid]  = 0.f;

    // persist the cnt row for the writer kernel
#pragma unroll
    for (int k = 0; k < 4; ++k)
        *reinterpret_cast<float4*>(&ws_cnt[(size_t)n * CC + (tid + 64 * k) * 4]) = v[k];
}

// ======================= Phase 2: streaming writer =======================
// One block = (n, 8 s-values). 256 threads, each owns 4 classes. Minimal
// prologue (4 KB cnt read + 8 lse + 80 ban ids), then 8 float4 stores/thread.
// Plain (cached) stores: output fits the 256 MiB L3, let it absorb.
__global__ __launch_bounds__(256) void spop_write_kernel(
    const int* __restrict__ ban_ids,    // [N,S,B]
    const float* __restrict__ ws_cnt,   // [N,C]
    const float* __restrict__ ws_lse,   // [N,S]
    float* __restrict__ out_pi)         // [N,S,C]
{
    const int tid = threadIdx.x;
    const int n   = blockIdx.x >> 3;               // SS/SH2 == 8
    const int s0  = (blockIdx.x & 7) * SH2;
    const int b0  = n * SS + s0;

    __shared__ unsigned mask[SH2][CC / 32];        // 1 KB: 1024-bit mask per s
    __shared__ float lse_s[SH2];

    reinterpret_cast<unsigned*>(mask)[tid] = 0u;   // 256 words, one per thread

    const float4 c4 =
        *reinterpret_cast<const float4*>(&ws_cnt[(size_t)n * CC + tid * 4]);
    if (tid < SH2) lse_s[tid] = ws_lse[b0 + tid];
    __syncthreads();

    if (tid < SH2 * BB) {                          // 80 ban scatters
        const int c = ban_ids[b0 * BB + tid];
        atomicOr(&mask[tid / BB][c >> 5], 1u << (c & 31));
    }
    __syncthreads();

    // hoist all LDS reads (conflict-free broadcasts), then burst the stores
    const int mword = tid >> 3;                    // (tid*4)>>5
    const int msh   = (tid & 7) * 4;
    float    lse_r[SH2];
    unsigned m4_r[SH2];
#pragma unroll
    for (int s = 0; s < SH2; ++s) {
        lse_r[s] = lse_s[s];
        m4_r[s]  = (mask[s][mword] >> msh) & 0xFu;
    }

    float4* obase = reinterpret_cast<float4*>(&out_pi[(size_t)b0 * CC]) + tid;
#pragma unroll
    for (int s = 0; s < SH2; ++s) {
        float4 v = c4;
        if (m4_r[s] & 1u) v.x -= 1e9f;
        if (m4_r[s] & 2u) v.y -= 1e9f;
        if (m4_r[s] & 4u) v.z -= 1e9f;
        if (m4_r[s] & 8u) v.w -= 1e9f;
        const float l = lse_r[s];
        obase[(size_t)s * (CC / 4)] =
            make_float4(v.x - l, v.y - l, v.z - l, v.w - l);
    }
}

// ======================= Fallback: original fused kernel =======================
__global__ __launch_bounds__(256) void spop_fused_kernel(
    const int* __restrict__ ban_ids,
    const int* __restrict__ item_ids,
    float* __restrict__ out_pi,
    float* __restrict__ out_v)
{
    const int tid  = threadIdx.x;
    const int lane = tid & 63;
    const int wid  = tid >> 6;
    const int n    = blockIdx.x >> 1;
    const int s0   = (blockIdx.x & 1) * SH;
    const int b0   = n * SS + s0;

    __shared__ __align__(16) float cnt[CC];
    __shared__ unsigned mask[SH][CC / 32];
    __shared__ int   bansh[SH * BB];
    __shared__ float lse_s[SH];
    __shared__ float red_m[4], red_s[4];

    *reinterpret_cast<float4*>(&cnt[tid * 4]) = make_float4(0.f, 0.f, 0.f, 0.f);
#pragma unroll
    for (int k = 0; k < 4; ++k) mask[0][tid + 256 * k] = 0u;
    __syncthreads();

    if (tid < 64) {
        int id = item_ids[n * SS + tid];
        bool nonpad = (id != 0);
        unsigned long long m = __ballot(nonpad);
        int last = 63 - __clzll(m | 1ull);
        if (nonpad && tid != last) atomicAdd(&cnt[id], 1.0f);
    }
    __syncthreads();

    const float4 c4 = *reinterpret_cast<const float4*>(&cnt[tid * 4]);

    float mx = fmaxf(fmaxf(c4.x, c4.y), fmaxf(c4.z, c4.w));
#pragma unroll
    for (int off = 32; off >= 1; off >>= 1)
        mx = fmaxf(mx, __shfl_xor(mx, off));
    if (lane == 0) red_m[wid] = mx;

    for (int i = tid; i < SH * BB; i += 256) {
        int c = ban_ids[b0 * BB + i];
        bansh[i] = c;
        atomicOr(&mask[i / BB][c >> 5], 1u << (c & 31));
    }
    __syncthreads();
    mx = fmaxf(fmaxf(red_m[0], red_m[1]), fmaxf(red_m[2], red_m[3]));

    float se = __expf(c4.x - mx) + __expf(c4.y - mx) +
               __expf(c4.z - mx) + __expf(c4.w - mx);
#pragma unroll
    for (int off = 32; off >= 1; off >>= 1)
        se += __shfl_xor(se, off);
    if (lane == 0) red_s[wid] = se;
    __syncthreads();
    const float sumall = red_s[0] + red_s[1] + red_s[2] + red_s[3];

    if (tid < SH) {
        int ban[BB];
#pragma unroll
        for (int j = 0; j < BB; ++j) ban[j] = bansh[tid * BB + j];
        float bsum = 0.f;
#pragma unroll
        for (int j = 0; j < BB; ++j) {
            bool dup = false;
#pragma unroll
            for (int k = 0; k < BB; ++k)
                if (k < j) dup |= (ban[k] == ban[j]);
            if (!dup) bsum += __expf(cnt[ban[j]] - mx);
        }
        float valid = fmaxf(sumall - bsum, 1e-30f);
        lse_s[tid] = mx + __logf(valid);
        out_v[b0 + tid] = 0.0f;
    }
    __syncthreads();

    const int mword = tid >> 3;
    const int msh   = (tid & 7) * 4;
    nfloat4* obase = reinterpret_cast<nfloat4*>(&out_pi[(size_t)b0 * CC]) + tid;

    float    lse_r[SH];
    unsigned m4_r[SH];
#pragma unroll
    for (int s = 0; s < SH; ++s) {
        lse_r[s] = lse_s[s];
        m4_r[s]  = (mask[s][mword] >> msh) & 0xF;
    }

#pragma unroll
    for (int s = 0; s < SH; ++s) {
        const float l = lse_r[s];
        const unsigned m4 = m4_r[s];
        float4 v = c4;
        if (m4 & 1u) v.x -= 1e9f;
        if (m4 & 2u) v.y -= 1e9f;
        if (m4 & 4u) v.z -= 1e9f;
        if (m4 & 8u) v.w -= 1e9f;
        nfloat4 nv = { v.x - l, v.y - l, v.z - l, v.w - l };
        __builtin_nontemporal_store(nv, obase + (size_t)s * (CC / 4));
    }
}

extern "C" void kernel_launch(void* const* d_in, const int* in_sizes, int n_in,
                              void* d_out, int out_size, void* d_ws, size_t ws_size,
                              hipStream_t stream) {
    const int* ban_ids  = (const int*)d_in[1];
    const int* item_ids = (const int*)d_in[2];
    float* out_pi = (float*)d_out;                      // [N,S,C]
    float* out_v  = out_pi + (size_t)NN * SS * CC;      // [N,S]

    const size_t need = ((size_t)NN * CC + (size_t)NN * SS) * sizeof(float);
    if (d_ws != nullptr && ws_size >= need) {
        float* ws_cnt = (float*)d_ws;                   // [N,C]
        float* ws_lse = ws_cnt + (size_t)NN * CC;       // [N,S]
        spop_stats_kernel<<<dim3(NN), dim3(64), 0, stream>>>(
            ban_ids, item_ids, ws_cnt, ws_lse, out_v);
        spop_write_kernel<<<dim3(NN * (SS / SH2)), dim3(256), 0, stream>>>(
            ban_ids, ws_cnt, ws_lse, out_pi);
    } else {
        spop_fused_kernel<<<dim3(NN * (SS / SH)), dim3(256), 0, stream>>>(
            ban_ids, item_ids, out_pi, out_v);
    }
}